// Round 7
// baseline (943.635 us; speedup 1.0000x reference)
//
#include <hip/hip_runtime.h>

#define H 128
#define NBIN 32

typedef __bf16 bf16_t;
typedef bf16_t bf16x8 __attribute__((ext_vector_type(8)));
typedef bf16_t bf16x4 __attribute__((ext_vector_type(4)));
typedef float f32x4 __attribute__((ext_vector_type(4)));
typedef unsigned int uint32;

// ---- f32 -> bf16 conversion (vectorized, total must be %4==0) ----
__global__ void k_conv4(const float* __restrict__ in, bf16_t* __restrict__ out, int total) {
    int idx = (blockIdx.x * blockDim.x + threadIdx.x) * 4;
    if (idx < total) {
        float4 v = *(const float4*)(in + idx);
        bf16x4 o;
        o[0] = (bf16_t)v.x; o[1] = (bf16_t)v.y; o[2] = (bf16_t)v.z; o[3] = (bf16_t)v.w;
        *(bf16x4*)(out + idx) = o;
    }
}

// ---- counting sort of edges by SOURCE bin, stage 1: per-block LDS histogram ----
__global__ void k_bincount(const int* __restrict__ row, int* __restrict__ bincnt,
                           int E, int NN) {
    __shared__ int h[NBIN];
    int tid = threadIdx.x;
    if (tid < NBIN) h[tid] = 0;
    __syncthreads();
    int e = blockIdx.x * 1024 + tid;
    if (e < E) {
        int b = (int)((long long)row[e] * NBIN / NN);
        atomicAdd(&h[b], 1);
    }
    __syncthreads();
    if (tid < NBIN) atomicAdd(&bincnt[tid], h[tid]);
}

// ---- tiny exclusive scan of bin counts -> bin cursors ----
__global__ void k_scan_bins(const int* __restrict__ bincnt, int* __restrict__ bincur) {
    if (blockIdx.x == 0 && threadIdx.x == 0) {
        int run = 0;
        for (int i = 0; i < NBIN; ++i) { int t = bincnt[i]; bincur[i] = run; run += t; }
    }
}

// ---- counting sort stage 2: place edges into source-bin-ordered arrays ----
// Per-block LDS histogram + one global cursor bump per bin per block keeps
// global atomics to 32/block and writes block-clustered within bin regions.
__global__ void k_binplace(const int* __restrict__ row, const int* __restrict__ col,
                           int* __restrict__ bincur, int* __restrict__ rowS,
                           int* __restrict__ colS, int E, int NN) {
    __shared__ int h[NBIN];
    __shared__ int base[NBIN];
    int tid = threadIdx.x;
    if (tid < NBIN) h[tid] = 0;
    __syncthreads();
    int e = blockIdx.x * 1024 + tid;
    int b = 0, slot = 0, r = 0, c = 0;
    bool ok = (e < E);
    if (ok) {
        r = row[e]; c = col[e];
        b = (int)((long long)r * NBIN / NN);
        slot = atomicAdd(&h[b], 1);
    }
    __syncthreads();
    if (tid < NBIN) base[tid] = atomicAdd(&bincur[tid], h[tid]);
    __syncthreads();
    if (ok) {
        int pos = base[b] + slot;
        rowS[pos] = r;
        colS[pos] = c;
    }
}

// ---- degree histogram, 2 nodes packed per u32, one destination-RANGE per pass ----
__global__ void k_hist_pass(const int* __restrict__ col, uint32* __restrict__ deg16,
                            int E, int lo, int hi) {
    int e = blockIdx.x * blockDim.x + threadIdx.x;
    if (e < E) {
        int c = col[e];
        if (c >= lo && c < hi)
            atomicAdd(deg16 + (c >> 1), (c & 1) ? 0x10000u : 1u);
    }
}

// ---- per-1024-chunk partial sums of packed deg ----
__global__ void k_partial(const uint32* __restrict__ deg16, int* __restrict__ partial, int NN) {
    __shared__ int s[256];
    int base = blockIdx.x * 1024 + threadIdx.x * 4;   // node index, multiple of 4
    int t = 0;
    if (base < NN) {
        uint32 a = deg16[base >> 1];
        uint32 b = (base + 2 < NN) ? deg16[(base >> 1) + 1] : 0u;
        t = (int)((a & 0xffffu) + (a >> 16) + (b & 0xffffu) + (b >> 16));
    }
    s[threadIdx.x] = t;
    __syncthreads();
    for (int off = 128; off > 0; off >>= 1) {
        if (threadIdx.x < off) s[threadIdx.x] += s[threadIdx.x + off];
        __syncthreads();
    }
    if (threadIdx.x == 0) partial[blockIdx.x] = s[0];
}

// ---- serial exclusive scan of the (tiny) partial array ----
__global__ void k_scan_partial(int* __restrict__ partial, int NB) {
    if (blockIdx.x == 0 && threadIdx.x == 0) {
        int run = 0;
        for (int i = 0; i < NB; ++i) { int t = partial[i]; partial[i] = run; run += t; }
    }
}

// ---- per-chunk exclusive scan -> CSC offsets, cursor copy, inv-degree ----
__global__ void k_offsets(const uint32* __restrict__ deg16, const int* __restrict__ partial,
                          int* __restrict__ offs, int* __restrict__ cursor,
                          float* __restrict__ invdeg, int NN, int E) {
    __shared__ int s[256];
    int tid = threadIdx.x;
    int base = blockIdx.x * 1024 + tid * 4;
    int d[4] = {0, 0, 0, 0};
    if (base < NN) {
        uint32 a = deg16[base >> 1];
        uint32 b = (base + 2 < NN) ? deg16[(base >> 1) + 1] : 0u;
        d[0] = (int)(a & 0xffffu); d[1] = (int)(a >> 16);
        d[2] = (int)(b & 0xffffu); d[3] = (int)(b >> 16);
    }
    int tsum = d[0] + d[1] + d[2] + d[3];
    s[tid] = tsum;
    __syncthreads();
    for (int off = 1; off < 256; off <<= 1) {
        int v = (tid >= off) ? s[tid - off] : 0;
        __syncthreads();
        s[tid] += v;
        __syncthreads();
    }
    int run = partial[blockIdx.x] + s[tid] - tsum;  // exclusive base for this thread
#pragma unroll
    for (int j = 0; j < 4; ++j) {
        int n = base + j;
        if (n < NN) {
            offs[n] = run;
            cursor[n] = run;
            int dd = d[j] > 1 ? d[j] : 1;
            invdeg[n] = 1.0f / (float)dd;
            run += d[j];
        }
    }
    if (blockIdx.x == 0 && tid == 0) offs[NN] = E;
}

// ---- bucket edges by destination, one destination-RANGE per pass ----
// Reads the SOURCE-BIN-SORTED edge list, so each destination segment of
// srcid ends up ordered by ascending source bin -> co-resident waves sweep
// x in a narrow band during the gather (L2 band locality).
__global__ void k_scatter_pass(const int* __restrict__ rowS, const int* __restrict__ colS,
                               int* __restrict__ cursor, int* __restrict__ srcid,
                               int E, int lo, int hi) {
    int e = blockIdx.x * blockDim.x + threadIdx.x;
    if (e < E) {
        int c = colS[e];
        if (c >= lo && c < hi) {
            int pos = atomicAdd(cursor + c, 1);
            srcid[pos] = rowS[e];
        }
    }
}

// ---- FUSED: mean-aggregate -> Linear(MFMA) -> ReLU -> residual ----
// State lives ONLY in the bf16 ping-pong mirrors between iterations. The
// final iteration (LAST=1) widens to f32 and writes d_out. 4-edge gather
// unroll: 16 independent 16B gathers in flight per lane.
template <int LAST>
__global__ __launch_bounds__(256) void k_fused(
    const bf16_t* __restrict__ xsrc, const int* __restrict__ offs,
    const int* __restrict__ srcid, const float* __restrict__ invdeg,
    const bf16_t* __restrict__ wbf, const float* __restrict__ bias,
    float* __restrict__ xnew, bf16_t* __restrict__ xdst, int NN)
{
    const int tid  = threadIdx.x;
    const int wid  = tid >> 6;
    const int lane = tid & 63;
    const int lr   = lane & 15;       // node-within-wave / A row / D col
    const int lg   = lane >> 4;       // feature group / k-group / D row-group
    const int m0   = blockIdx.x * 64 + wid * 16;

    int n = m0 + lr;
    if (n >= NN) n = NN - 1;          // clamped rows: outputs not stored
    const int e0 = offs[n], e1 = offs[n + 1];

    float acc[4][8];
#pragma unroll
    for (int kk = 0; kk < 4; ++kk)
#pragma unroll
        for (int j = 0; j < 8; ++j) acc[kk][j] = 0.f;

    const bf16_t* xb = xsrc + lg * 8;
    int e = e0;
    // 4-edge unroll: 16 independent 16B gathers in flight per lane
    while (e + 3 < e1) {
        int s0 = srcid[e];
        int s1 = srcid[e + 1];
        int s2 = srcid[e + 2];
        int s3 = srcid[e + 3];
        const bf16_t* r0 = xb + (size_t)s0 * H;
        const bf16_t* r1 = xb + (size_t)s1 * H;
        const bf16_t* r2 = xb + (size_t)s2 * H;
        const bf16_t* r3 = xb + (size_t)s3 * H;
        bf16x8 v0[4], v1[4], v2[4], v3[4];
#pragma unroll
        for (int kk = 0; kk < 4; ++kk) v0[kk] = *(const bf16x8*)(r0 + kk * 32);
#pragma unroll
        for (int kk = 0; kk < 4; ++kk) v1[kk] = *(const bf16x8*)(r1 + kk * 32);
#pragma unroll
        for (int kk = 0; kk < 4; ++kk) v2[kk] = *(const bf16x8*)(r2 + kk * 32);
#pragma unroll
        for (int kk = 0; kk < 4; ++kk) v3[kk] = *(const bf16x8*)(r3 + kk * 32);
#pragma unroll
        for (int kk = 0; kk < 4; ++kk)
#pragma unroll
            for (int j = 0; j < 8; ++j)
                acc[kk][j] += ((float)v0[kk][j] + (float)v1[kk][j])
                            + ((float)v2[kk][j] + (float)v3[kk][j]);
        e += 4;
    }
    while (e < e1) {
        int s0 = srcid[e];
        const bf16_t* r0 = xb + (size_t)s0 * H;
#pragma unroll
        for (int kk = 0; kk < 4; ++kk) {
            bf16x8 v = *(const bf16x8*)(r0 + kk * 32);
#pragma unroll
            for (int j = 0; j < 8; ++j) acc[kk][j] += (float)v[j];
        }
        ++e;
    }

    const float inv = invdeg[n];
    bf16x8 afrag[4];
#pragma unroll
    for (int kk = 0; kk < 4; ++kk)
#pragma unroll
        for (int j = 0; j < 8; ++j) afrag[kk][j] = (bf16_t)(acc[kk][j] * inv);

    f32x4 o[8] = {};
#pragma unroll
    for (int kk = 0; kk < 4; ++kk) {
#pragma unroll
        for (int c = 0; c < 8; ++c) {
            bf16x8 b = *(const bf16x8*)(wbf + (size_t)(c * 16 + lr) * H + kk * 32 + lg * 8);
            o[c] = __builtin_amdgcn_mfma_f32_16x16x32_bf16(afrag[kk], b, o[c], 0, 0, 0);
        }
    }

#pragma unroll
    for (int c = 0; c < 8; ++c) {
        int colN = c * 16 + lr;
        float bv = bias[colN];
#pragma unroll
        for (int j = 0; j < 4; ++j) {
            int r = m0 + lg * 4 + j;
            if (r < NN) {
                float v = o[c][j] + bv;
                v = fmaxf(v, 0.f);
                size_t off = (size_t)r * H + colN;
                float xn = (float)xsrc[off] + v;   // residual from bf16 state
                if (LAST)
                    xnew[off] = xn;                // final f32 output
                else
                    xdst[off] = (bf16_t)xn;        // next iteration's state
            }
        }
    }
}

extern "C" void kernel_launch(void* const* d_in, const int* in_sizes, int n_in,
                              void* d_out, int out_size, void* d_ws, size_t ws_size,
                              hipStream_t stream) {
    const float* x_in  = (const float*)d_in[0];
    const int*   erow  = (const int*)d_in[1];
    const float* W     = (const float*)d_in[2];
    const float* bias  = (const float*)d_in[3];

    const int NN = in_sizes[0] / H;      // 100000
    const int E  = in_sizes[1] / 2;      // 1600000
    const int* ecol = erow + E;

    float* xout = (float*)d_out;

    // workspace carve (256B aligned regions)
    char* p = (char*)d_ws;
    auto carve = [&](size_t bytes) -> char* {
        char* r = p;
        p += (bytes + 255) & ~(size_t)255;
        return r;
    };
    bf16_t* xbufA  = (bf16_t*)carve((size_t)NN * H * 2);
    bf16_t* xbufB  = (bf16_t*)carve((size_t)NN * H * 2);
    bf16_t* wbf    = (bf16_t*)carve((size_t)H * H * 2);
    uint32* deg16  = (uint32*)carve((size_t)(NN / 2 + 1) * 4);
    int*    offs   = (int*)carve((size_t)(NN + 1) * 4);
    int*    cursor = (int*)carve((size_t)NN * 4);
    float*  invdeg = (float*)carve((size_t)NN * 4);
    int*    srcid  = (int*)carve((size_t)E * 4);
    int*    rowS   = (int*)carve((size_t)E * 4);
    int*    colS   = (int*)carve((size_t)E * 4);
    int*    bincnt = (int*)carve((size_t)NBIN * 4);
    int*    bincur = (int*)carve((size_t)NBIN * 4);
    int*    partial= (int*)carve((size_t)((NN + 1023) / 1024) * 4);

    const int NB = (NN + 1023) / 1024;
    const int NPASS = 4;
    // window step: multiple of 2 so packed deg16 pairs never straddle windows
    const int step = ((NN + NPASS - 1) / NPASS + 1) & ~1;
    const int EB1024 = (E + 1023) / 1024;

    // ---- one-time setup per call ----
    k_conv4<<<(NN * H / 4 + 255) / 256, 256, 0, stream>>>(x_in, xbufA, NN * H);
    k_conv4<<<(H * H / 4 + 255) / 256, 256, 0, stream>>>(W, wbf, H * H);

    // counting sort edges by source bin
    hipMemsetAsync(bincnt, 0, (size_t)NBIN * 4, stream);
    k_bincount<<<EB1024, 1024, 0, stream>>>(erow, bincnt, E, NN);
    k_scan_bins<<<1, 64, 0, stream>>>(bincnt, bincur);
    k_binplace<<<EB1024, 1024, 0, stream>>>(erow, ecol, bincur, rowS, colS, E, NN);

    // degree histogram (dest-windowed passes for write locality)
    hipMemsetAsync(deg16, 0, (size_t)(NN / 2 + 1) * 4, stream);
    for (int pass = 0; pass < NPASS; ++pass) {
        int lo = pass * step;
        int hi = (pass == NPASS - 1) ? NN : (lo + step < NN ? lo + step : NN);
        if (lo >= NN) break;
        k_hist_pass<<<(E + 255) / 256, 256, 0, stream>>>(colS, deg16, E, lo, hi);
    }
    k_partial<<<NB, 256, 0, stream>>>(deg16, partial, NN);
    k_scan_partial<<<1, 64, 0, stream>>>(partial, NB);
    k_offsets<<<NB, 256, 0, stream>>>(deg16, partial, offs, cursor, invdeg, NN, E);

    // dest-windowed scatter over the source-sorted edge list
    for (int pass = 0; pass < NPASS; ++pass) {
        int lo = pass * step;
        int hi = (pass == NPASS - 1) ? NN : (lo + step < NN ? lo + step : NN);
        if (lo >= NN) break;
        k_scatter_pass<<<(E + 255) / 256, 256, 0, stream>>>(rowS, colS, cursor, srcid, E, lo, hi);
    }

    // ---- 6 fused message-passing iterations (bf16 state ping-pong) ----
    bf16_t* xb[2] = {xbufA, xbufB};
    const int grid = (NN + 63) / 64;
    for (int it = 0; it < 5; ++it) {
        k_fused<0><<<grid, 256, 0, stream>>>(xb[it & 1], offs, srcid, invdeg, wbf, bias,
                                             xout, xb[(it & 1) ^ 1], NN);
    }
    k_fused<1><<<grid, 256, 0, stream>>>(xb[5 & 1], offs, srcid, invdeg, wbf, bias,
                                         xout, xb[0], NN);
}

// Round 8
// 874.024 us; speedup vs baseline: 1.0796x; 1.0796x over previous
//
#include <hip/hip_runtime.h>

#define H 128

typedef __bf16 bf16_t;
typedef bf16_t bf16x8 __attribute__((ext_vector_type(8)));
typedef bf16_t bf16x4 __attribute__((ext_vector_type(4)));
typedef float f32x4 __attribute__((ext_vector_type(4)));
typedef unsigned int uint32;

// ---- f32 -> bf16 conversion (vectorized, total must be %4==0) ----
__global__ void k_conv4(const float* __restrict__ in, bf16_t* __restrict__ out, int total) {
    int idx = (blockIdx.x * blockDim.x + threadIdx.x) * 4;
    if (idx < total) {
        float4 v = *(const float4*)(in + idx);
        bf16x4 o;
        o[0] = (bf16_t)v.x; o[1] = (bf16_t)v.y; o[2] = (bf16_t)v.z; o[3] = (bf16_t)v.w;
        *(bf16x4*)(out + idx) = o;
    }
}

// ---- degree histogram, 2 nodes packed per u32, one destination-RANGE per pass ----
__global__ void k_hist_pass(const int* __restrict__ col, uint32* __restrict__ deg16,
                            int E, int lo, int hi) {
    int e = blockIdx.x * blockDim.x + threadIdx.x;
    if (e < E) {
        int c = col[e];
        if (c >= lo && c < hi)
            atomicAdd(deg16 + (c >> 1), (c & 1) ? 0x10000u : 1u);
    }
}

// ---- per-1024-chunk partial sums of packed deg ----
__global__ void k_partial(const uint32* __restrict__ deg16, int* __restrict__ partial, int NN) {
    __shared__ int s[256];
    int base = blockIdx.x * 1024 + threadIdx.x * 4;   // node index, multiple of 4
    int t = 0;
    if (base < NN) {
        uint32 a = deg16[base >> 1];
        uint32 b = (base + 2 < NN) ? deg16[(base >> 1) + 1] : 0u;
        t = (int)((a & 0xffffu) + (a >> 16) + (b & 0xffffu) + (b >> 16));
    }
    s[threadIdx.x] = t;
    __syncthreads();
    for (int off = 128; off > 0; off >>= 1) {
        if (threadIdx.x < off) s[threadIdx.x] += s[threadIdx.x + off];
        __syncthreads();
    }
    if (threadIdx.x == 0) partial[blockIdx.x] = s[0];
}

// ---- serial exclusive scan of the (tiny) partial array ----
__global__ void k_scan_partial(int* __restrict__ partial, int NB) {
    if (blockIdx.x == 0 && threadIdx.x == 0) {
        int run = 0;
        for (int i = 0; i < NB; ++i) { int t = partial[i]; partial[i] = run; run += t; }
    }
}

// ---- per-chunk exclusive scan -> CSC offsets, cursor copy, inv-degree ----
__global__ void k_offsets(const uint32* __restrict__ deg16, const int* __restrict__ partial,
                          int* __restrict__ offs, int* __restrict__ cursor,
                          float* __restrict__ invdeg, int NN, int E) {
    __shared__ int s[256];
    int tid = threadIdx.x;
    int base = blockIdx.x * 1024 + tid * 4;
    int d[4] = {0, 0, 0, 0};
    if (base < NN) {
        uint32 a = deg16[base >> 1];
        uint32 b = (base + 2 < NN) ? deg16[(base >> 1) + 1] : 0u;
        d[0] = (int)(a & 0xffffu); d[1] = (int)(a >> 16);
        d[2] = (int)(b & 0xffffu); d[3] = (int)(b >> 16);
    }
    int tsum = d[0] + d[1] + d[2] + d[3];
    s[tid] = tsum;
    __syncthreads();
    for (int off = 1; off < 256; off <<= 1) {
        int v = (tid >= off) ? s[tid - off] : 0;
        __syncthreads();
        s[tid] += v;
        __syncthreads();
    }
    int run = partial[blockIdx.x] + s[tid] - tsum;  // exclusive base for this thread
#pragma unroll
    for (int j = 0; j < 4; ++j) {
        int n = base + j;
        if (n < NN) {
            offs[n] = run;
            cursor[n] = run;
            int dd = d[j] > 1 ? d[j] : 1;
            invdeg[n] = 1.0f / (float)dd;
            run += d[j];
        }
    }
    if (blockIdx.x == 0 && tid == 0) offs[NN] = E;
}

// ---- bucket edges by destination, one destination-RANGE per pass ----
__global__ void k_scatter_pass(const int* __restrict__ row, const int* __restrict__ col,
                               int* __restrict__ cursor, int* __restrict__ srcid,
                               int E, int lo, int hi) {
    int e = blockIdx.x * blockDim.x + threadIdx.x;
    if (e < E) {
        int c = col[e];
        if (c >= lo && c < hi) {
            int pos = atomicAdd(cursor + c, 1);
            srcid[pos] = row[e];
        }
    }
}

// ---- per-node segmented mean-aggregate (atomic-free), bf16 in/out ----
// One node per WAVE, quarter-wave (16 lanes) per edge slot; each lane loads
// bf16x8 (16B). 4-edge unroll -> 16 independent gathers in flight per wave.
// LOW VGPR (~40) -> high occupancy -> many outstanding L2 misses; the gather
// is concurrency-bound (fused 80-VGPR variant at 26% occupancy ran 2x slower).
__global__ __launch_bounds__(256) void k_agg(const bf16_t* __restrict__ xbf, const int* __restrict__ offs,
                                             const int* __restrict__ srcid, const float* __restrict__ invdeg,
                                             bf16_t* __restrict__ msg, int NN) {
    const int wid  = threadIdx.x >> 6;
    const int lane = threadIdx.x & 63;
    const int n    = blockIdx.x * 4 + wid;
    if (n >= NN) return;
    const int qid = lane >> 4;     // edge slot 0..3
    const int f   = lane & 15;     // feature group: 8f .. 8f+7

    const int e0 = offs[n], e1 = offs[n + 1];

    float acc[8] = {0.f, 0.f, 0.f, 0.f, 0.f, 0.f, 0.f, 0.f};

    int e = e0 + qid;
    // 4-edge unrolled main loop: four independent row gathers in flight
    while (e + 12 < e1) {
        int s0 = srcid[e];
        int s1 = srcid[e + 4];
        int s2 = srcid[e + 8];
        int s3 = srcid[e + 12];
        bf16x8 v0 = *(const bf16x8*)(xbf + (size_t)s0 * H + f * 8);
        bf16x8 v1 = *(const bf16x8*)(xbf + (size_t)s1 * H + f * 8);
        bf16x8 v2 = *(const bf16x8*)(xbf + (size_t)s2 * H + f * 8);
        bf16x8 v3 = *(const bf16x8*)(xbf + (size_t)s3 * H + f * 8);
#pragma unroll
        for (int j = 0; j < 8; ++j)
            acc[j] += ((float)v0[j] + (float)v1[j]) + ((float)v2[j] + (float)v3[j]);
        e += 16;
    }
    while (e < e1) {
        int s0 = srcid[e];
        bf16x8 v0 = *(const bf16x8*)(xbf + (size_t)s0 * H + f * 8);
#pragma unroll
        for (int j = 0; j < 8; ++j) acc[j] += (float)v0[j];
        e += 4;
    }

    // reduce across the 4 quarter-waves (feature groups align across quarters)
#pragma unroll
    for (int j = 0; j < 8; ++j) {
        acc[j] += __shfl_xor(acc[j], 16);
        acc[j] += __shfl_xor(acc[j], 32);
    }

    if (qid == 0) {
        float inv = invdeg[n];
        bf16x8 o;
#pragma unroll
        for (int j = 0; j < 8; ++j) o[j] = (bf16_t)(acc[j] * inv);
        *(bf16x8*)(msg + (size_t)n * H + f * 8) = o;
    }
}

// ---- MFMA GEMM + epilogue on bf16 state: out = xsrc + relu(msg @ W^T + b) ----
// State lives only in the bf16 ping-pong mirrors; the final iteration
// (LAST=1) widens to f32 and writes d_out instead of a mirror.
template <int LAST>
__global__ __launch_bounds__(256) void k_gemm2(
    const bf16_t* __restrict__ msg, const bf16_t* __restrict__ wbf,
    const float* __restrict__ bias, const bf16_t* __restrict__ xsrc,
    float* __restrict__ xnew, bf16_t* __restrict__ xdst, int NN)
{
    const int tid = threadIdx.x;
    const int wid = tid >> 6;          // wave 0..3
    const int lane = tid & 63;
    const int lr = lane & 15;          // A row / B col / D col
    const int lg = lane >> 4;          // k-group / D row-group
    const int m0 = blockIdx.x * 64 + wid * 16;   // wave's 16 output rows

    f32x4 acc[8] = {};
    int ar = m0 + lr;
    if (ar >= NN) ar = NN - 1;         // clamp: garbage rows only feed unstored outputs
    const bf16_t* arow = msg + (size_t)ar * H;

#pragma unroll
    for (int kk = 0; kk < 4; ++kk) {
        bf16x8 a = *(const bf16x8*)(arow + kk * 32 + lg * 8);
#pragma unroll
        for (int c = 0; c < 8; ++c) {
            bf16x8 b = *(const bf16x8*)(wbf + (size_t)(c * 16 + lr) * H + kk * 32 + lg * 8);
            acc[c] = __builtin_amdgcn_mfma_f32_16x16x32_bf16(a, b, acc[c], 0, 0, 0);
        }
    }

#pragma unroll
    for (int c = 0; c < 8; ++c) {
        int colN = c * 16 + lr;
        float bv = bias[colN];
#pragma unroll
        for (int j = 0; j < 4; ++j) {
            int r = m0 + lg * 4 + j;
            if (r < NN) {
                float v = acc[c][j] + bv;
                v = fmaxf(v, 0.f);
                size_t off = (size_t)r * H + colN;
                float xn = (float)xsrc[off] + v;   // residual from bf16 state
                if (LAST)
                    xnew[off] = xn;                // final f32 output
                else
                    xdst[off] = (bf16_t)xn;        // next iteration's state
            }
        }
    }
}

extern "C" void kernel_launch(void* const* d_in, const int* in_sizes, int n_in,
                              void* d_out, int out_size, void* d_ws, size_t ws_size,
                              hipStream_t stream) {
    const float* x_in  = (const float*)d_in[0];
    const int*   erow  = (const int*)d_in[1];
    const float* W     = (const float*)d_in[2];
    const float* bias  = (const float*)d_in[3];

    const int NN = in_sizes[0] / H;      // 100000
    const int E  = in_sizes[1] / 2;      // 1600000
    const int* ecol = erow + E;

    float* xout = (float*)d_out;

    // workspace carve (256B aligned regions)
    char* p = (char*)d_ws;
    auto carve = [&](size_t bytes) -> char* {
        char* r = p;
        p += (bytes + 255) & ~(size_t)255;
        return r;
    };
    bf16_t* xbufA  = (bf16_t*)carve((size_t)NN * H * 2);
    bf16_t* xbufB  = (bf16_t*)carve((size_t)NN * H * 2);
    bf16_t* msg    = (bf16_t*)carve((size_t)NN * H * 2);
    bf16_t* wbf    = (bf16_t*)carve((size_t)H * H * 2);
    uint32* deg16  = (uint32*)carve((size_t)(NN / 2 + 1) * 4);
    int*    offs   = (int*)carve((size_t)(NN + 1) * 4);
    int*    cursor = (int*)carve((size_t)NN * 4);
    float*  invdeg = (float*)carve((size_t)NN * 4);
    int*    srcid  = (int*)carve((size_t)E * 4);
    int*    partial= (int*)carve((size_t)((NN + 1023) / 1024) * 4);

    const int NB = (NN + 1023) / 1024;
    const int NPASS = 4;
    // window step: multiple of 2 so packed deg16 pairs never straddle windows
    const int step = ((NN + NPASS - 1) / NPASS + 1) & ~1;

    // ---- one-time setup per call ----
    k_conv4<<<(NN * H / 4 + 255) / 256, 256, 0, stream>>>(x_in, xbufA, NN * H);
    k_conv4<<<(H * H / 4 + 255) / 256, 256, 0, stream>>>(W, wbf, H * H);
    hipMemsetAsync(deg16, 0, (size_t)(NN / 2 + 1) * 4, stream);
    for (int pass = 0; pass < NPASS; ++pass) {
        int lo = pass * step;
        int hi = (pass == NPASS - 1) ? NN : (lo + step < NN ? lo + step : NN);
        if (lo >= NN) break;
        k_hist_pass<<<(E + 255) / 256, 256, 0, stream>>>(ecol, deg16, E, lo, hi);
    }
    k_partial<<<NB, 256, 0, stream>>>(deg16, partial, NN);
    k_scan_partial<<<1, 64, 0, stream>>>(partial, NB);
    k_offsets<<<NB, 256, 0, stream>>>(deg16, partial, offs, cursor, invdeg, NN, E);

    // binned scatter: sequential destination-range passes for write locality
    for (int pass = 0; pass < NPASS; ++pass) {
        int lo = pass * step;
        int hi = (pass == NPASS - 1) ? NN : (lo + step < NN ? lo + step : NN);
        if (lo >= NN) break;
        k_scatter_pass<<<(E + 255) / 256, 256, 0, stream>>>(erow, ecol, cursor, srcid, E, lo, hi);
    }

    // ---- 6 message-passing iterations: gather (high-occupancy) + MFMA (streaming) ----
    bf16_t* xb[2] = {xbufA, xbufB};
    const int gridA = (NN + 3) / 4;
    const int gridG = (NN + 63) / 64;
    for (int it = 0; it < 6; ++it) {
        bf16_t* xs = xb[it & 1];
        bf16_t* xd = xb[(it & 1) ^ 1];
        k_agg<<<gridA, 256, 0, stream>>>(xs, offs, srcid, invdeg, msg, NN);
        if (it < 5)
            k_gemm2<0><<<gridG, 256, 0, stream>>>(msg, wbf, bias, xs, xout, xd, NN);
        else
            k_gemm2<1><<<gridG, 256, 0, stream>>>(msg, wbf, bias, xs, xout, xd, NN);
    }
}